// Round 17
// baseline (424.475 us; speedup 1.0000x reference)
//
#include <hip/hip_runtime.h>

#define NV 8192
#define NC 128
#define VP 64
#define FP 124
#define MAXSLOT 26   // bbox half-extent <= 0.5, spacing 0.8 -> <=26 neighbors
#define NSL 7        // max slots per wave = ceil(26/4)

typedef unsigned long long ull;

// ---- lock-free union-find on global parent[] ----
// parent[x] <= x, monotone decreasing. Hooks only "commit" when the RMW
// return proves the target was a root; otherwise retry with the old value.
__device__ __forceinline__ int findro(const int* parent, int x) {
  int p = parent[x];
  while (p != x) { x = p; p = parent[x]; }
  return x;
}
__device__ __forceinline__ void ghook(int* parent, int a0, int b0) {
  int a = a0, b = b0;
  for (;;) {
    a = findro(parent, a);
    b = findro(parent, b);
    if (a == b) break;
    int hi = a > b ? a : b, lo = a > b ? b : a;
    int old = atomicMin(&parent[hi], lo);
    if (old == hi) { a = lo; b = lo; break; }
    a = old; b = lo;
  }
  int r = a < b ? a : b;
  if (r < a0) atomicMin(&parent[a0], r);   // one-shot path compression (safe:
  if (r < b0) atomicMin(&parent[b0], r);   // r is a root of a0/b0's component)
}

// Vertex reconstruction from group-mean sums (identical expression at every
// call site -> bitwise-identical coordinates in all blocks).
__device__ __forceinline__ void recon3(const float* ps1, const float* ps2,
                                       const float* pc, int l,
                                       float& x, float& y, float& z) {
  float cc = fmaxf(pc[l], 1.f);
  x = ps1[3*l+0]/cc + 1e-5f*(ps2[3*l+0]/cc);
  y = ps1[3*l+1]/cc + 1e-5f*(ps2[3*l+1]/cc);
  z = ps1[3*l+2]/cc + 1e-5f*(ps2[3*l+2]/cc);
}

// Shared adjacency derivation: parity-balanced pair ownership.
__device__ __forceinline__ int build_adj(const float* bb, int c, int q, int v,
                                         int t, int* s_hcell, ull* s_adjw,
                                         int* s_KH) {
  if (q < 2) {
    int b = q * 64 + v;
    float anx = bb[c*6+0], any_ = bb[c*6+1], anz = bb[c*6+2];
    float axx = bb[c*6+3], axy = bb[c*6+4], axz = bb[c*6+5];
    float bnx = bb[b*6+0], bny = bb[b*6+1], bnz = bb[b*6+2];
    float bxx = bb[b*6+3], bxy = bb[b*6+4], bxz = bb[b*6+5];
    bool ov = (b != c) && (anx <= bxx) && (any_ <= bxy) && (anz <= bxz) &&
              (bnx <= axx) && (bny <= axy) && (bnz <= axz);
    bool mine = ov && (((c + b) & 1) ? (b < c) : (b > c));
    ull w = __ballot(mine);
    if (v == 0) s_adjw[q] = w;
  }
  __syncthreads();
  if (t == 0) {
    int slot = 0;
    for (int wd = 0; wd < 2; ++wd) {
      ull aw = s_adjw[wd];
      while (aw) {
        int bbit = __ffsll((long long)aw) - 1; aw &= aw - 1;
        if (slot < MAXSLOT) s_hcell[slot] = wd * 64 + bbit;
        ++slot;
      }
    }
    *s_KH = slot;
  }
  __syncthreads();
  return *s_KH;
}

__global__ void k_init(int* __restrict__ parent) {
  int i = blockIdx.x * blockDim.x + threadIdx.x;
  if (i < NV) parent[i] = i;
}

// K1: stage verts, contact masks, Warshall closure, AND all UF hooks.
// Own chain via ghook (race-safe); cross hooks grouped by local label L
// (clique-uniform, read from LDS -- no divergent shfl): leader hooks
// (L_root, j_lead), members hook (j, j_lead).
__global__ __launch_bounds__(256, 1)
void k_contact(int it, const float* __restrict__ inV, const float* __restrict__ bb,
               const int* __restrict__ labelsF, const float* __restrict__ ps1,
               const float* __restrict__ pc, const float* __restrict__ ps2,
               float* __restrict__ verts, int* __restrict__ parent) {
  const float T2 = (float)(0.3 * 0.3);
  const int c = blockIdx.x;
  const int t = threadIdx.x;
  const int q = t >> 6;
  const int v = t & 63;

  __shared__ float s_vx[VP], s_vy[VP], s_vz[VP], s_sq[VP];
  __shared__ int   s_hcell[MAXSLOT];
  __shared__ int   s_KH;
  __shared__ int   s_llv[VP];
  __shared__ ull   s_adjw[2];
  __shared__ ull   s_Mw[4][VP];   // per-wave adjacency rows for merge

  const int KH = build_adj(bb, c, q, v, t, s_hcell, s_adjw, &s_KH);

  if (t < VP) {
    int i = c*VP + t;
    float x, y, z;
    if (it == 0) { x = inV[3*i+0]; y = inV[3*i+1]; z = inV[3*i+2]; }
    else         { recon3(ps1, ps2, pc, labelsF[i], x, y, z); }
    s_vx[t] = x; s_vy[t] = y; s_vz[t] = z; s_sq[t] = x*x + y*y + z*z;
    verts[3*i+0] = x; verts[3*i+1] = y; verts[3*i+2] = z;  // for K2's scatter
  }
  __syncthreads();

  ull msk[NSL];
  {
    float xs[NSL], ys[NSL], zs[NSL];
#pragma unroll
    for (int s = 0; s < NSL; ++s) {
      msk[s] = 0;
      int slot = q + 4*s;
      if (slot < KH) {
        int jb = s_hcell[slot]*VP;
        if (it == 0) {
          int j = jb + v;
          xs[s] = inV[3*j+0]; ys[s] = inV[3*j+1]; zs[s] = inV[3*j+2];
        } else {
          int lF = labelsF[jb + v];
          recon3(ps1, ps2, pc, lF, xs[s], ys[s], zs[s]);
        }
      }
    }
#pragma unroll
    for (int s = 0; s < NSL; ++s) { int slot = q + 4*s; if (slot < KH) {
      float X = xs[s], Y = ys[s], Z = zs[s];
      float sqj = X*X + Y*Y + Z*Z;
      ull w = 0;
      for (int vv = 0; vv < VP; ++vv) {
        float d2 = s_sq[vv] + sqj - 2.f*(s_vx[vv]*X + s_vy[vv]*Y + s_vz[vv]*Z);
        if (d2 < T2) w |= (1ull << vv);
      }
      msk[s] = w;
    } }
  }

  // Own-vert adjacency rows: lane v holds M_v = {own verts sharing a clique
  // with v} | {v}. Clique of neighbor-lane k in slot s = shfl(msk[s], k).
  ull M = 1ull << v;
#pragma unroll
  for (int s = 0; s < NSL; ++s) {
    ull any = __ballot(msk[s] != 0);   // wave-uniform guard
    if (any) {
#pragma unroll
      for (int k = 0; k < 64; ++k) {
        ull ck = __shfl(msk[s], k);
        if ((ck >> v) & 1) M |= ck;
      }
    }
  }
  // Merge the 4 waves' partial rows (different slots) via LDS.
  s_Mw[q][v] = M;
  __syncthreads();
  M = s_Mw[0][v] | s_Mw[1][v] | s_Mw[2][v] | s_Mw[3][v];
  // Single-pass in-wave Floyd-Warshall: full transitive closure in 64 steps.
#pragma unroll
  for (int k = 0; k < 64; ++k) {
    ull rk = __shfl(M, k);
    if ((M >> k) & 1) M |= rk;
  }
  const int ll = __ffsll((long long)M) - 1;   // local component min (all waves)
  if (q == 0) s_llv[v] = ll;                  // publish for divergent lookups
  __syncthreads();

  // own chain: RACE-SAFE hook (cross hooks from other blocks may touch our
  // verts concurrently -- a bare atomicMin can drop verified unions).
  if (q == 0 && ll != v) ghook(parent, c*VP + v, c*VP + ll);

  // cross hooks with per-slot local-label dedupe; L read from LDS (lane-
  // activity independent, unlike shfl-under-divergence).
#pragma unroll
  for (int s = 0; s < NSL; ++s) { int slot = q + 4*s; if (slot < KH) {
    int jb = s_hcell[slot]*VP;
    ull w = msk[s];
    int L = -1;
    if (w) L = s_llv[__ffsll((long long)w) - 1];  // clique-uniform
    int myj = jb + v;
    ull act = __ballot(w != 0);
    while (act) {
      int lead = __ffsll((long long)act) - 1;
      int Ll = __shfl(L,   lead);
      int jl = __shfl(myj, lead);
      ull grp = __ballot(L == Ll && w != 0) & act;
      if ((grp >> v) & 1) {
        if (v == lead) ghook(parent, c*VP + Ll, myj);
        else           ghook(parent, myj, jl);
      }
      act &= ~grp;
    }
  } }
}

// K2: find labels, publish, zero prev parity, scatter vert sums.
__global__ __launch_bounds__(64, 1)
void k_find(const int* __restrict__ parent, int* __restrict__ labelsF,
            const float* __restrict__ verts,
            float* __restrict__ cs1, float* __restrict__ cc1,
            float* __restrict__ zs1, float* __restrict__ zc,
            float* __restrict__ zs2) {
  const int c = blockIdx.x, t = threadIdx.x;
  __shared__ int   s_lab[VP];
  __shared__ float s_vx[VP], s_vy[VP], s_vz[VP];
  int i = c*VP + t;
  int l = findro(parent, i);
  s_lab[t] = l;
  labelsF[i] = l;
  s_vx[t] = verts[3*i+0]; s_vy[t] = verts[3*i+1]; s_vz[t] = verts[3*i+2];
  for (int idx = t; idx < VP*3; idx += VP) {
    zs1[c*VP*3 + idx] = 0.f;
    zs2[c*VP*3 + idx] = 0.f;
  }
  zc[i] = 0.f;
  __syncthreads();
  {
    bool leader = true;
    for (int s = 0; s < t; ++s) if (s_lab[s] == l) { leader = false; break; }
    if (leader) {
      float sx = 0.f, sy = 0.f, sz = 0.f, cn = 0.f;
      for (int s = t; s < VP; ++s)
        if (s_lab[s] == l) { sx += s_vx[s]; sy += s_vy[s]; sz += s_vz[s]; cn += 1.f; }
      atomicAdd(&cs1[3*l+0], sx);
      atomicAdd(&cs1[3*l+1], sy);
      atomicAdd(&cs1[3*l+2], sz);
      atomicAdd(&cc1[l], cn);
    }
  }
}

// K3: gather group-mean verts, cell forces, scatter force sums, parent reinit.
__global__ __launch_bounds__(128, 1)
void k_forces(const int* __restrict__ labelsF, const int* __restrict__ faces,
              const int* __restrict__ cfl, const float* __restrict__ pP,
              const float* __restrict__ pS,
              const float* __restrict__ cs1, const float* __restrict__ cc1,
              float* __restrict__ cs2, int* __restrict__ parent) {
  const int c = blockIdx.x, t = threadIdx.x;
  __shared__ float s_vx[VP], s_vy[VP], s_vz[VP];
  __shared__ float s_gx[VP], s_gy[VP], s_gz[VP];
  __shared__ float s_fx[VP], s_fy[VP], s_fz[VP];
  __shared__ int   s_lab[VP];
  __shared__ float s_cx, s_cy, s_cz, s_vol, s_csx, s_csy, s_csz;

  if (t < VP) {
    int i = c*VP + t;
    int l = labelsF[i];
    s_lab[t] = l;
    float cc = fmaxf(cc1[l], 1.f);
    s_vx[t] = cs1[3*l+0] / cc;
    s_vy[t] = cs1[3*l+1] / cc;
    s_vz[t] = cs1[3*l+2] / cc;
    s_gx[t] = 0.f; s_gy[t] = 0.f; s_gz[t] = 0.f;
    parent[i] = i;   // reinit for next iteration
  }
  if (t == 0) { s_vol = 0.f; s_csx = 0.f; s_csy = 0.f; s_csz = 0.f; }
  __syncthreads();
  if (t < VP) {
    float sx = s_vx[t], sy = s_vy[t], sz = s_vz[t];
#pragma unroll
    for (int o = 32; o; o >>= 1) { sx += __shfl_xor(sx, o); sy += __shfl_xor(sy, o); sz += __shfl_xor(sz, o); }
    if (t == 0) { s_cx = sx*(1.f/VP); s_cy = sy*(1.f/VP); s_cz = sz*(1.f/VP); }
  }
  __syncthreads();
  float cx = s_cx, cy = s_cy, cz = s_cz;
  bool act = (t < FP);
  int ia = 0, ib = 0, ic = 0;
  float p0x=0,p0y=0,p0z=0,p1x=0,p1y=0,p1z=0,p2x=0,p2y=0,p2z=0;
  float q0x=0,q0y=0,q0z=0;
  if (act) {
    int f = cfl[c*FP + t];
    ia = faces[3*f+0] - c*VP; ib = faces[3*f+1] - c*VP; ic = faces[3*f+2] - c*VP;
    p0x = s_vx[ia]-cx; p0y = s_vy[ia]-cy; p0z = s_vz[ia]-cz;
    p1x = s_vx[ib]-cx; p1y = s_vy[ib]-cy; p1z = s_vz[ib]-cz;
    p2x = s_vx[ic]-cx; p2y = s_vy[ic]-cy; p2z = s_vz[ic]-cz;
    q0x = p1y*p2z - p1z*p2y;
    q0y = p1z*p2x - p1x*p2z;
    q0z = p1x*p2y - p1y*p2x;
    float term = p0x*q0x + p0y*q0y + p0z*q0z;
    atomicAdd(&s_vol, term);
  }
  __syncthreads();
  float press = pP[0]*190.f + 10.f;
  float st    = pS[0]*0.018f + 0.002f;
  float tv    = expf(press / 2500.f);
  float vol   = s_vol / 6.f;
  float coeff = 2500.f * (vol - tv);
  if (act) {
    float q1x = p2y*p0z - p2z*p0y;
    float q1y = p2z*p0x - p2x*p0z;
    float q1z = p2x*p0y - p2y*p0x;
    float q2x = p0y*p1z - p0z*p1y;
    float q2y = p0z*p1x - p0x*p1z;
    float q2z = p0x*p1y - p0y*p1x;
    float e1x = p1x-p0x, e1y = p1y-p0y, e1z = p1z-p0z;
    float e2x = p2x-p0x, e2y = p2y-p0y, e2z = p2z-p0z;
    float nx = e1y*e2z - e1z*e2y;
    float ny = e1z*e2x - e1x*e2z;
    float nz = e1x*e2y - e1y*e2x;
    float S  = nx*nx + ny*ny + nz*nz + 1e-12f;
    float wt = st / (2.f * sqrtf(S));
    float dx = e1x-e2x, dy = e1y-e2y, dz = e1z-e2z;
    float g0x = wt*(dy*nz - dz*ny), g0y = wt*(dz*nx - dx*nz), g0z = wt*(dx*ny - dy*nx);
    float g1x = wt*(e2y*nz - e2z*ny), g1y = wt*(e2z*nx - e2x*nz), g1z = wt*(e2x*ny - e2y*nx);
    float g2x = wt*(ny*e1z - nz*e1y), g2y = wt*(nz*e1x - nx*e1z), g2z = wt*(nx*e1y - ny*e1x);
    float k = coeff / 6.f;
    atomicAdd(&s_gx[ia], g0x + k*q0x); atomicAdd(&s_gy[ia], g0y + k*q0y); atomicAdd(&s_gz[ia], g0z + k*q0z);
    atomicAdd(&s_gx[ib], g1x + k*q1x); atomicAdd(&s_gy[ib], g1y + k*q1y); atomicAdd(&s_gz[ib], g1z + k*q1z);
    atomicAdd(&s_gx[ic], g2x + k*q2x); atomicAdd(&s_gy[ic], g2y + k*q2y); atomicAdd(&s_gz[ic], g2z + k*q2z);
    atomicAdd(&s_csx, q0x+q1x+q2x);
    atomicAdd(&s_csy, q0y+q1y+q2y);
    atomicAdd(&s_csz, q0z+q1z+q2z);
  }
  __syncthreads();
  if (t < VP) {
    float corr = coeff / 384.f;   // coeff * (1/6) * (1/64) centroid chain
    s_fx[t] = -(s_gx[t] - corr*s_csx);
    s_fy[t] = -(s_gy[t] - corr*s_csy);
    s_fz[t] = -(s_gz[t] - corr*s_csz);
  }
  __syncthreads();
  if (t < VP) {
    int l = s_lab[t];
    bool leader = true;
    for (int s = 0; s < t; ++s) if (s_lab[s] == l) { leader = false; break; }
    if (leader) {
      float sx = 0.f, sy = 0.f, sz = 0.f;
      for (int s = t; s < VP; ++s)
        if (s_lab[s] == l) { sx += s_fx[s]; sy += s_fy[s]; sz += s_fz[s]; }
      atomicAdd(&cs2[3*l+0], sx);
      atomicAdd(&cs2[3*l+1], sy);
      atomicAdd(&cs2[3*l+2], sz);
    }
  }
}

// K4: final output = group-mean verts + dt * group-mean forces (iter 4).
__global__ __launch_bounds__(64, 1)
void k_out(const int* __restrict__ labelsF, const float* __restrict__ cs1,
           const float* __restrict__ cc1, const float* __restrict__ cs2,
           float* __restrict__ out) {
  const int c = blockIdx.x, t = threadIdx.x;
  int i = c*VP + t;
  int l = labelsF[i];
  float cc = fmaxf(cc1[l], 1.f);
  out[3*i+0] = cs1[3*l+0]/cc + 1e-5f*(cs2[3*l+0]/cc);
  out[3*i+1] = cs1[3*l+1]/cc + 1e-5f*(cs2[3*l+1]/cc);
  out[3*i+2] = cs1[3*l+2]/cc + 1e-5f*(cs2[3*l+2]/cc);
}

extern "C" void kernel_launch(void* const* d_in, const int* in_sizes, int n_in,
                              void* d_out, int out_size, void* d_ws, size_t ws_size,
                              hipStream_t stream) {
  const float* inV   = (const float*)d_in[0];
  const float* bb    = (const float*)d_in[1];
  const float* pP    = (const float*)d_in[2];
  const float* pS    = (const float*)d_in[3];
  const int*   faces = (const int*)d_in[4];
  const int*   cfl   = (const int*)d_in[6];

  char* w = (char*)d_ws;
  int*   parent  = (int*)w;   w += NV*sizeof(int);          // 32 KB
  int*   labelsF = (int*)w;   w += NV*sizeof(int);          // 32 KB
  float* verts   = (float*)w; w += NV*3*sizeof(float);      // 96 KB
  float* zbase   = (float*)w;                               // contiguous zero region:
  float* sumsA   = (float*)w; w += 2*NV*3*sizeof(float);    // 192 KB (2 parities)
  float* countsA = (float*)w; w += 2*NV*sizeof(float);      // 64 KB
  float* sumsB   = (float*)w; w += 2*NV*3*sizeof(float);    // 192 KB

  hipMemsetAsync(zbase, 0, (2*NV*3 + 2*NV + 2*NV*3)*sizeof(float), stream);
  k_init<<<NV/256, 256, 0, stream>>>(parent);

  for (int it = 0; it < 5; ++it) {
    const int p = it & 1;
    float* cs1 = sumsA + p*(NV*3);
    float* cc1 = countsA + p*NV;
    float* cs2 = sumsB + p*(NV*3);
    float* ps1 = sumsA + (p^1)*(NV*3);
    float* pc  = countsA + (p^1)*NV;
    float* ps2 = sumsB + (p^1)*(NV*3);

    k_contact<<<NC, 256, 0, stream>>>(it, inV, bb, labelsF, ps1, pc, ps2,
                                      verts, parent);
    k_find<<<NC, 64, 0, stream>>>(parent, labelsF, verts,
                                  cs1, cc1, ps1, pc, ps2);
    k_forces<<<NC, 128, 0, stream>>>(labelsF, faces, cfl, pP, pS,
                                     cs1, cc1, cs2, parent);
  }
  // iter 4 parity = 0
  k_out<<<NC, 64, 0, stream>>>(labelsF, sumsA, countsA, sumsB, (float*)d_out);
}

// Round 18
// 371.612 us; speedup vs baseline: 1.1423x; 1.1423x over previous
//
#include <hip/hip_runtime.h>

#define NV 8192
#define NC 128
#define VP 64
#define FP 124
#define MAXSLOT 26   // bbox half-extent <= 0.5, spacing 0.8 -> <=26 neighbors
#define NW 8         // waves per block in k_contact / k_hook
#define NSL 4        // max slots per wave = ceil(26/8)

typedef unsigned long long ull;

// ---- lock-free union-find on global parent[] (quotient space only) ----
__device__ __forceinline__ int findro(const int* parent, int x) {
  int p = parent[x];
  while (p != x) { x = p; p = parent[x]; }
  return x;
}
__device__ __forceinline__ void ghook(int* parent, int a0, int b0) {
  int a = a0, b = b0;
  for (;;) {
    a = findro(parent, a);
    b = findro(parent, b);
    if (a == b) break;
    int hi = a > b ? a : b, lo = a > b ? b : a;
    int old = atomicMin(&parent[hi], lo);
    if (old == hi) { a = lo; b = lo; break; }
    a = old; b = lo;
  }
  int r = a < b ? a : b;
  if (r < a0) atomicMin(&parent[a0], r);   // one-shot path compression
  if (r < b0) atomicMin(&parent[b0], r);
}

// Shared adjacency derivation: parity-balanced pair ownership.
__device__ __forceinline__ int build_adj(const float* bb, int c, int q, int v,
                                         int t, int* s_hcell, ull* s_adjw,
                                         int* s_KH) {
  if (q < 2) {
    int b = q * 64 + v;
    float anx = bb[c*6+0], any_ = bb[c*6+1], anz = bb[c*6+2];
    float axx = bb[c*6+3], axy = bb[c*6+4], axz = bb[c*6+5];
    float bnx = bb[b*6+0], bny = bb[b*6+1], bnz = bb[b*6+2];
    float bxx = bb[b*6+3], bxy = bb[b*6+4], bxz = bb[b*6+5];
    bool ov = (b != c) && (anx <= bxx) && (any_ <= bxy) && (anz <= bxz) &&
              (bnx <= axx) && (bny <= axy) && (bnz <= axz);
    bool mine = ov && (((c + b) & 1) ? (b < c) : (b > c));
    ull w = __ballot(mine);
    if (v == 0) s_adjw[q] = w;
  }
  __syncthreads();
  if (t == 0) {
    int slot = 0;
    for (int wd = 0; wd < 2; ++wd) {
      ull aw = s_adjw[wd];
      while (aw) {
        int bbit = __ffsll((long long)aw) - 1; aw &= aw - 1;
        if (slot < MAXSLOT) s_hcell[slot] = wd * 64 + bbit;
        ++slot;
      }
    }
    *s_KH = slot;
  }
  __syncthreads();
  return *s_KH;
}

__global__ void k_init(int* __restrict__ parent) {
  int i = blockIdx.x * blockDim.x + threadIdx.x;
  if (i < NV) parent[i] = i;
}

// K1: stage verts (input or float4 recon), contact masks, Warshall closure.
// Publishes llab + masks; NO global UF work (quotient hooks live in k_hook).
__global__ __launch_bounds__(512, 1)
void k_contact(int it, const float* __restrict__ inV, const float* __restrict__ bb,
               const int* __restrict__ labelsF, const float4* __restrict__ ps1,
               const float4* __restrict__ ps2,
               float4* __restrict__ verts4, int* __restrict__ llab,
               ull* __restrict__ masks) {
  const float T2 = (float)(0.3 * 0.3);
  const int c = blockIdx.x;
  const int t = threadIdx.x;
  const int q = t >> 6;    // wave 0..7
  const int v = t & 63;

  __shared__ float s_vx[VP], s_vy[VP], s_vz[VP], s_sq[VP];
  __shared__ int   s_hcell[MAXSLOT];
  __shared__ int   s_KH;
  __shared__ ull   s_adjw[2];
  __shared__ ull   s_Mw[NW][VP];

  const int KH = build_adj(bb, c, q, v, t, s_hcell, s_adjw, &s_KH);

  if (t < VP) {
    int i = c*VP + t;
    float x, y, z;
    if (it == 0) { x = inV[3*i+0]; y = inV[3*i+1]; z = inV[3*i+2]; }
    else {
      int l = labelsF[i];
      float4 a = ps1[l], b = ps2[l];
      float cc = fmaxf(a.w, 1.f);
      x = a.x/cc + 1e-5f*(b.x/cc);
      y = a.y/cc + 1e-5f*(b.y/cc);
      z = a.z/cc + 1e-5f*(b.z/cc);
    }
    s_vx[t] = x; s_vy[t] = y; s_vz[t] = z; s_sq[t] = x*x + y*y + z*z;
    verts4[i] = make_float4(x, y, z, 0.f);   // for K3's scatter
  }
  __syncthreads();

  ull msk[NSL];
  {
    float xs[NSL], ys[NSL], zs[NSL];
#pragma unroll
    for (int s = 0; s < NSL; ++s) {
      msk[s] = 0;
      int slot = q + NW*s;
      if (slot < KH) {
        int jb = s_hcell[slot]*VP;
        if (it == 0) {
          int j = jb + v;
          xs[s] = inV[3*j+0]; ys[s] = inV[3*j+1]; zs[s] = inV[3*j+2];
        } else {
          int l = labelsF[jb + v];
          float4 a = ps1[l], b = ps2[l];
          float cc = fmaxf(a.w, 1.f);
          xs[s] = a.x/cc + 1e-5f*(b.x/cc);
          ys[s] = a.y/cc + 1e-5f*(b.y/cc);
          zs[s] = a.z/cc + 1e-5f*(b.z/cc);
        }
      }
    }
#pragma unroll
    for (int s = 0; s < NSL; ++s) { int slot = q + NW*s; if (slot < KH) {
      float X = xs[s], Y = ys[s], Z = zs[s];
      float sqj = X*X + Y*Y + Z*Z;
      ull w = 0;
      for (int vv = 0; vv < VP; ++vv) {
        float d2 = s_sq[vv] + sqj - 2.f*(s_vx[vv]*X + s_vy[vv]*Y + s_vz[vv]*Z);
        if (d2 < T2) w |= (1ull << vv);
      }
      msk[s] = w;
      masks[((size_t)c*MAXSLOT + slot)*VP + v] = w;
    } }
  }

  // Own-vert adjacency rows: lane v holds M_v = {own verts sharing a clique
  // with v} | {v}. Clique of neighbor-lane k in slot s = shfl(msk[s], k).
  ull M = 1ull << v;
#pragma unroll
  for (int s = 0; s < NSL; ++s) {
    ull any = __ballot(msk[s] != 0);   // wave-uniform guard
    if (any) {
#pragma unroll
      for (int k = 0; k < 64; ++k) {
        ull ck = __shfl(msk[s], k);
        if ((ck >> v) & 1) M |= ck;
      }
    }
  }
  // Merge the 8 waves' partial rows via LDS.
  s_Mw[q][v] = M;
  __syncthreads();
  M = s_Mw[0][v] | s_Mw[1][v] | s_Mw[2][v] | s_Mw[3][v] |
      s_Mw[4][v] | s_Mw[5][v] | s_Mw[6][v] | s_Mw[7][v];
  // Single-pass in-wave Floyd-Warshall: full transitive closure in 64 steps.
#pragma unroll
  for (int k = 0; k < 64; ++k) {
    ull rk = __shfl(M, k);
    if ((M >> k) & 1) M |= rk;
  }
  if (q == 0) llab[c*VP + v] = c*VP + (__ffsll((long long)M) - 1);
}

// K2: quotient-space hooks. Both sides' local labels visible -> wave-dedupe
// identical (L, Lb) pairs; only group leaders hook. No per-vertex hooks:
// k_find resolves via findro(parent, llab[i]).
__global__ __launch_bounds__(512, 1)
void k_hook(const float* __restrict__ bb, const int* __restrict__ llab,
            const ull* __restrict__ masks, int* __restrict__ parent) {
  const int c = blockIdx.x;
  const int t = threadIdx.x;
  const int q = t >> 6;
  const int v = t & 63;

  __shared__ int s_hcell[MAXSLOT];
  __shared__ int s_KH;
  __shared__ ull s_adjw[2];

  const int KH = build_adj(bb, c, q, v, t, s_hcell, s_adjw, &s_KH);

#pragma unroll
  for (int s = 0; s < NSL; ++s) { int slot = q + NW*s; if (slot < KH) {
    int jb = s_hcell[slot]*VP;
    ull w = masks[((size_t)c*MAXSLOT + slot)*VP + v];
    int L = -1, Lb = -1;
    if (w) {
      L  = llab[c*VP + (__ffsll((long long)w) - 1)];  // clique-uniform
      Lb = llab[jb + v];
    }
    ull act = __ballot(w != 0);
    while (act) {
      int lead = __ffsll((long long)act) - 1;
      int Ll  = __shfl(L,  lead);
      int Lbl = __shfl(Lb, lead);
      ull grp = __ballot(L == Ll && Lb == Lbl && w != 0) & act;
      if (v == lead) ghook(parent, Ll, Lbl);
      act &= ~grp;
    }
  } }
}

// K3: find labels (from llab), publish, zero prev parity, scatter vert sums.
__global__ __launch_bounds__(64, 1)
void k_find(const int* __restrict__ parent, const int* __restrict__ llab,
            int* __restrict__ labelsF, const float4* __restrict__ verts4,
            float4* __restrict__ cs1, float4* __restrict__ zs1,
            float4* __restrict__ zs2) {
  const int c = blockIdx.x, t = threadIdx.x;
  __shared__ int   s_lab[VP];
  __shared__ float s_vx[VP], s_vy[VP], s_vz[VP];
  int i = c*VP + t;
  int l = findro(parent, llab[i]);
  s_lab[t] = l;
  labelsF[i] = l;
  float4 vv = verts4[i];
  s_vx[t] = vv.x; s_vy[t] = vv.y; s_vz[t] = vv.z;
  zs1[i] = make_float4(0.f, 0.f, 0.f, 0.f);  // prev parity ready for it+1
  zs2[i] = make_float4(0.f, 0.f, 0.f, 0.f);
  __syncthreads();
  {
    bool leader = true;
    for (int s = 0; s < t; ++s) if (s_lab[s] == l) { leader = false; break; }
    if (leader) {
      float sx = 0.f, sy = 0.f, sz = 0.f, cn = 0.f;
      for (int s = t; s < VP; ++s)
        if (s_lab[s] == l) { sx += s_vx[s]; sy += s_vy[s]; sz += s_vz[s]; cn += 1.f; }
      atomicAdd(&cs1[l].x, sx);
      atomicAdd(&cs1[l].y, sy);
      atomicAdd(&cs1[l].z, sz);
      atomicAdd(&cs1[l].w, cn);
    }
  }
}

// K4: gather group-mean verts, cell forces, scatter force sums, parent reinit.
__global__ __launch_bounds__(128, 1)
void k_forces(const int* __restrict__ labelsF, const int* __restrict__ faces,
              const int* __restrict__ cfl, const float* __restrict__ pP,
              const float* __restrict__ pS,
              const float4* __restrict__ cs1, float4* __restrict__ cs2,
              int* __restrict__ parent) {
  const int c = blockIdx.x, t = threadIdx.x;
  __shared__ float s_vx[VP], s_vy[VP], s_vz[VP];
  __shared__ float s_gx[VP], s_gy[VP], s_gz[VP];
  __shared__ float s_fx[VP], s_fy[VP], s_fz[VP];
  __shared__ int   s_lab[VP];
  __shared__ float s_cx, s_cy, s_cz, s_vol, s_csx, s_csy, s_csz;

  if (t < VP) {
    int i = c*VP + t;
    int l = labelsF[i];
    s_lab[t] = l;
    float4 a = cs1[l];
    float cc = fmaxf(a.w, 1.f);
    s_vx[t] = a.x / cc;
    s_vy[t] = a.y / cc;
    s_vz[t] = a.z / cc;
    s_gx[t] = 0.f; s_gy[t] = 0.f; s_gz[t] = 0.f;
    parent[i] = i;   // reinit for next iteration
  }
  if (t == 0) { s_vol = 0.f; s_csx = 0.f; s_csy = 0.f; s_csz = 0.f; }
  __syncthreads();
  if (t < VP) {
    float sx = s_vx[t], sy = s_vy[t], sz = s_vz[t];
#pragma unroll
    for (int o = 32; o; o >>= 1) { sx += __shfl_xor(sx, o); sy += __shfl_xor(sy, o); sz += __shfl_xor(sz, o); }
    if (t == 0) { s_cx = sx*(1.f/VP); s_cy = sy*(1.f/VP); s_cz = sz*(1.f/VP); }
  }
  __syncthreads();
  float cx = s_cx, cy = s_cy, cz = s_cz;
  bool act = (t < FP);
  int ia = 0, ib = 0, ic = 0;
  float p0x=0,p0y=0,p0z=0,p1x=0,p1y=0,p1z=0,p2x=0,p2y=0,p2z=0;
  float q0x=0,q0y=0,q0z=0;
  if (act) {
    int f = cfl[c*FP + t];
    ia = faces[3*f+0] - c*VP; ib = faces[3*f+1] - c*VP; ic = faces[3*f+2] - c*VP;
    p0x = s_vx[ia]-cx; p0y = s_vy[ia]-cy; p0z = s_vz[ia]-cz;
    p1x = s_vx[ib]-cx; p1y = s_vy[ib]-cy; p1z = s_vz[ib]-cz;
    p2x = s_vx[ic]-cx; p2y = s_vy[ic]-cy; p2z = s_vz[ic]-cz;
    q0x = p1y*p2z - p1z*p2y;
    q0y = p1z*p2x - p1x*p2z;
    q0z = p1x*p2y - p1y*p2x;
    float term = p0x*q0x + p0y*q0y + p0z*q0z;
    atomicAdd(&s_vol, term);
  }
  __syncthreads();
  float press = pP[0]*190.f + 10.f;
  float st    = pS[0]*0.018f + 0.002f;
  float tv    = expf(press / 2500.f);
  float vol   = s_vol / 6.f;
  float coeff = 2500.f * (vol - tv);
  if (act) {
    float q1x = p2y*p0z - p2z*p0y;
    float q1y = p2z*p0x - p2x*p0z;
    float q1z = p2x*p0y - p2y*p0x;
    float q2x = p0y*p1z - p0z*p1y;
    float q2y = p0z*p1x - p0x*p1z;
    float q2z = p0x*p1y - p0y*p1x;
    float e1x = p1x-p0x, e1y = p1y-p0y, e1z = p1z-p0z;
    float e2x = p2x-p0x, e2y = p2y-p0y, e2z = p2z-p0z;
    float nx = e1y*e2z - e1z*e2y;
    float ny = e1z*e2x - e1x*e2z;
    float nz = e1x*e2y - e1y*e2x;
    float S  = nx*nx + ny*ny + nz*nz + 1e-12f;
    float wt = st / (2.f * sqrtf(S));
    float dx = e1x-e2x, dy = e1y-e2y, dz = e1z-e2z;
    float g0x = wt*(dy*nz - dz*ny), g0y = wt*(dz*nx - dx*nz), g0z = wt*(dx*ny - dy*nx);
    float g1x = wt*(e2y*nz - e2z*ny), g1y = wt*(e2z*nx - e2x*nz), g1z = wt*(e2x*ny - e2y*nx);
    float g2x = wt*(ny*e1z - nz*e1y), g2y = wt*(nz*e1x - nx*e1z), g2z = wt*(nx*e1y - ny*e1x);
    float k = coeff / 6.f;
    atomicAdd(&s_gx[ia], g0x + k*q0x); atomicAdd(&s_gy[ia], g0y + k*q0y); atomicAdd(&s_gz[ia], g0z + k*q0z);
    atomicAdd(&s_gx[ib], g1x + k*q1x); atomicAdd(&s_gy[ib], g1y + k*q1y); atomicAdd(&s_gz[ib], g1z + k*q1z);
    atomicAdd(&s_gx[ic], g2x + k*q2x); atomicAdd(&s_gy[ic], g2y + k*q2y); atomicAdd(&s_gz[ic], g2z + k*q2z);
    atomicAdd(&s_csx, q0x+q1x+q2x);
    atomicAdd(&s_csy, q0y+q1y+q2y);
    atomicAdd(&s_csz, q0z+q1z+q2z);
  }
  __syncthreads();
  if (t < VP) {
    float corr = coeff / 384.f;   // coeff * (1/6) * (1/64) centroid chain
    s_fx[t] = -(s_gx[t] - corr*s_csx);
    s_fy[t] = -(s_gy[t] - corr*s_csy);
    s_fz[t] = -(s_gz[t] - corr*s_csz);
  }
  __syncthreads();
  if (t < VP) {
    int l = s_lab[t];
    bool leader = true;
    for (int s = 0; s < t; ++s) if (s_lab[s] == l) { leader = false; break; }
    if (leader) {
      float sx = 0.f, sy = 0.f, sz = 0.f;
      for (int s = t; s < VP; ++s)
        if (s_lab[s] == l) { sx += s_fx[s]; sy += s_fy[s]; sz += s_fz[s]; }
      atomicAdd(&cs2[l].x, sx);
      atomicAdd(&cs2[l].y, sy);
      atomicAdd(&cs2[l].z, sz);
    }
  }
}

// K5: final output = group-mean verts + dt * group-mean forces (iter 4).
__global__ __launch_bounds__(64, 1)
void k_out(const int* __restrict__ labelsF, const float4* __restrict__ cs1,
           const float4* __restrict__ cs2, float* __restrict__ out) {
  const int c = blockIdx.x, t = threadIdx.x;
  int i = c*VP + t;
  int l = labelsF[i];
  float4 a = cs1[l], b = cs2[l];
  float cc = fmaxf(a.w, 1.f);
  out[3*i+0] = a.x/cc + 1e-5f*(b.x/cc);
  out[3*i+1] = a.y/cc + 1e-5f*(b.y/cc);
  out[3*i+2] = a.z/cc + 1e-5f*(b.z/cc);
}

extern "C" void kernel_launch(void* const* d_in, const int* in_sizes, int n_in,
                              void* d_out, int out_size, void* d_ws, size_t ws_size,
                              hipStream_t stream) {
  const float* inV   = (const float*)d_in[0];
  const float* bb    = (const float*)d_in[1];
  const float* pP    = (const float*)d_in[2];
  const float* pS    = (const float*)d_in[3];
  const int*   faces = (const int*)d_in[4];
  const int*   cfl   = (const int*)d_in[6];

  char* w = (char*)d_ws;
  int*    parent  = (int*)w;    w += NV*sizeof(int);           // 32 KB
  int*    labelsF = (int*)w;    w += NV*sizeof(int);           // 32 KB
  int*    llab    = (int*)w;    w += NV*sizeof(int);           // 32 KB
  float4* verts4  = (float4*)w; w += NV*sizeof(float4);        // 128 KB
  float4* zbase   = (float4*)w;                                // contiguous zero region:
  float4* sumsA   = (float4*)w; w += 2*NV*sizeof(float4);      // 256 KB (2 parities, xyz+cnt)
  float4* sumsB   = (float4*)w; w += 2*NV*sizeof(float4);      // 256 KB (force sums)
  ull*    masks   = (ull*)w;    w += (size_t)NC*MAXSLOT*VP*sizeof(ull);  // 1.66 MB

  hipMemsetAsync(zbase, 0, 4*NV*sizeof(float4), stream);
  k_init<<<NV/256, 256, 0, stream>>>(parent);

  for (int it = 0; it < 5; ++it) {
    const int p = it & 1;
    float4* cs1 = sumsA + p*NV;
    float4* cs2 = sumsB + p*NV;
    float4* ps1 = sumsA + (p^1)*NV;
    float4* ps2 = sumsB + (p^1)*NV;

    k_contact<<<NC, 512, 0, stream>>>(it, inV, bb, labelsF, ps1, ps2,
                                      verts4, llab, masks);
    k_hook<<<NC, 512, 0, stream>>>(bb, llab, masks, parent);
    k_find<<<NC, 64, 0, stream>>>(parent, llab, labelsF, verts4,
                                  cs1, ps1, ps2);
    k_forces<<<NC, 128, 0, stream>>>(labelsF, faces, cfl, pP, pS,
                                     cs1, cs2, parent);
  }
  // iter 4 parity = 0
  k_out<<<NC, 64, 0, stream>>>(labelsF, sumsA, sumsB, (float*)d_out);
}